// Round 3
// baseline (312.183 us; speedup 1.0000x reference)
//
#include <hip/hip_runtime.h>

// Problem constants: B=256, IN=256, H=256, L=2, S=128 (SLOTS=129)
// All float tensors are f32 (reference dtype); op/pos are int32. Output f32.

static __device__ __forceinline__ float sigf(float x) {
    return 1.0f / (1.0f + __expf(-x));
}
static __device__ __forceinline__ float tanh_fast(float x) {
    return 2.0f / (1.0f + __expf(-2.0f * x)) - 1.0f;
}

// ---------------------------------------------------------------------------
// Gather: x -> A0[:,0:256]; hidden[pos,b,:,0] -> A0[:,256:512];
// hidden[pos,b,:,1] -> A1[:,256:512]; cell gathers -> c0in/c1in.
__global__ __launch_bounds__(256) void gather_k(
    const float* __restrict__ x,
    const float* __restrict__ hid,
    const float* __restrict__ cel,
    const int* __restrict__ pos,
    float* __restrict__ A0, float* __restrict__ A1,
    float* __restrict__ c0in, float* __restrict__ c1in)
{
    int e = blockIdx.x * 256 + threadIdx.x;   // 65536 = B*H
    int b = e >> 8, h = e & 255;
    int p = pos[b];
    int base2 = ((p * 256 + b) * 256 + h) * 2;   // (s,b,h,l) flat, l fastest
    float2 hv = *(const float2*)&hid[base2];
    float2 cv = *(const float2*)&cel[base2];
    A0[b * 512 + h]       = x[e];
    A0[b * 512 + 256 + h] = hv.x;   // l=0
    A1[b * 512 + 256 + h] = hv.y;   // l=1
    c0in[e] = cv.x;
    c1in[e] = cv.y;
}

// ---------------------------------------------------------------------------
// GEMM: gates(256x1024) = A(256x512) @ [w_ih | w_hh]^T + b_ih + b_hh (all f32)
#define BM 32
#define BN 64
#define BK 16

__global__ __launch_bounds__(256) void gemm_k(
    const float* __restrict__ A,
    const float* __restrict__ wih,   // 1024 x 256
    const float* __restrict__ whh,   // 1024 x 256
    const float* __restrict__ bih,
    const float* __restrict__ bhh,
    float* __restrict__ gates)
{
    __shared__ float As[BK][BM + 2];   // row stride 34 floats
    __shared__ float Ws[BK][BN + 4];   // row stride 68 floats
    int t = threadIdx.x;
    int bm0 = (blockIdx.x >> 4) * BM;  // 8 row tiles
    int jt0 = (blockIdx.x & 15) * BN;  // 16 col tiles
    int am = t >> 3;                   // [0,32) A row
    int ac = (t & 7) * 2;              // A k-local (float2)
    int wr = t >> 2;                   // [0,64) W row (j-local)
    int wc = (t & 3) * 4;              // W k-local (float4)
    int tx = t & 15, ty = t >> 4;
    float acc[2][4] = {{0.f,0.f,0.f,0.f},{0.f,0.f,0.f,0.f}};
    for (int kt = 0; kt < 512; kt += BK) {
        float2 av = *(const float2*)&A[(bm0 + am) * 512 + kt + ac];
        int j = jt0 + wr;
        int kk = kt + wc;
        const float* wsrc = (kk < 256) ? &wih[j * 256 + kk]
                                       : &whh[j * 256 + kk - 256];
        float4 wv = *(const float4*)wsrc;
        __syncthreads();
        As[ac][am]     = av.x;
        As[ac + 1][am] = av.y;
        Ws[wc][wr]     = wv.x;
        Ws[wc + 1][wr] = wv.y;
        Ws[wc + 2][wr] = wv.z;
        Ws[wc + 3][wr] = wv.w;
        __syncthreads();
        #pragma unroll
        for (int k = 0; k < BK; ++k) {
            float2 a  = *(const float2*)&As[k][ty * 2];
            float4 bv = *(const float4*)&Ws[k][tx * 4];
            acc[0][0] = fmaf(a.x, bv.x, acc[0][0]);
            acc[0][1] = fmaf(a.x, bv.y, acc[0][1]);
            acc[0][2] = fmaf(a.x, bv.z, acc[0][2]);
            acc[0][3] = fmaf(a.x, bv.w, acc[0][3]);
            acc[1][0] = fmaf(a.y, bv.x, acc[1][0]);
            acc[1][1] = fmaf(a.y, bv.y, acc[1][1]);
            acc[1][2] = fmaf(a.y, bv.z, acc[1][2]);
            acc[1][3] = fmaf(a.y, bv.w, acc[1][3]);
        }
    }
    #pragma unroll
    for (int m = 0; m < 2; ++m) {
        int b = bm0 + ty * 2 + m;
        #pragma unroll
        for (int n = 0; n < 4; ++n) {
            int j = jt0 + tx * 4 + n;
            gates[b * 1024 + j] = acc[m][n] + bih[j] + bhh[j];
        }
    }
}

// ---------------------------------------------------------------------------
// Activation: torch gate order i,f,g,o
__global__ __launch_bounds__(256) void act_k(
    const float* __restrict__ gates,
    const float* __restrict__ cin,
    float* __restrict__ hdst, int hstride,
    float* __restrict__ cdst)
{
    int e = blockIdx.x * 256 + threadIdx.x;   // 65536
    int b = e >> 8, h = e & 255;
    const float* g = gates + b * 1024 + h;
    float gi = g[0], gf = g[256], gg = g[512], go = g[768];
    float c  = sigf(gf) * cin[e] + sigf(gi) * tanh_fast(gg);
    float hn = sigf(go) * tanh_fast(c);
    hdst[b * hstride + h] = hn;
    cdst[e] = c;
}

// ---------------------------------------------------------------------------
// Copy both stacks to d_out (f32) with the pos+1 slot replaced; one extra
// block writes h_out/c_out. float4 = 4 elems = 2 h-values x 2 layers.
#define NV4_PER_STACK 4227072     // 129*256*256*2/4
#define NCOPY_BLOCKS  33024       // 2*NV4_PER_STACK/256 (exact)
#define STACK_ELEMS   16908288    // 129*256*256*2

__global__ __launch_bounds__(256) void copy_k(
    const float* __restrict__ hid, const float* __restrict__ cel,
    const int* __restrict__ pos, const int* __restrict__ op,
    const float* __restrict__ A1,     // h0 at [b*512 + h] (cols 0:256)
    const float* __restrict__ h1f,    // h1 at [b*256 + h]
    const float* __restrict__ c0f, const float* __restrict__ c1f,
    float* __restrict__ out)
{
    if (blockIdx.x == NCOPY_BLOCKS) {
        // finalize: h_out (1,B,L) at out[0..511], c_out at out[512..1023]
        int b = threadIdx.x;
        int o = op[b];
        float h0v, h1v, c0v, c1v;
        if (o == 1) {           // new_pos == pos+1: freshly computed slot
            h0v = A1[b * 512 + 255];
            h1v = h1f[b * 256 + 255];
            c0v = c0f[b * 256 + 255];
            c1v = c1f[b * 256 + 255];
        } else {                // untouched slot: passthrough from input
            int np = pos[b] + o;
            int base2 = ((np * 256 + b) * 256 + 255) * 2;
            h0v = hid[base2]; h1v = hid[base2 + 1];
            c0v = cel[base2]; c1v = cel[base2 + 1];
        }
        out[b * 2]           = h0v;
        out[b * 2 + 1]       = h1v;
        out[512 + b * 2]     = c0v;
        out[512 + b * 2 + 1] = c1v;
        return;
    }
    int v = blockIdx.x * 256 + threadIdx.x;
    bool is_cell = v >= NV4_PER_STACK;
    int vv = is_cell ? v - NV4_PER_STACK : v;
    int s   = vv >> 15;        // / (256*128): float4s per slot = 32768
    int rem = vv & 32767;
    int b   = rem >> 7;        // float4s per (b) plane = 128
    int q   = rem & 127;       // covers elems 4q..4q+3 = (h=2q..2q+1, l=0..1)
    float4 val;
    if (s == pos[b] + 1) {
        int h = q * 2;
        const float* l0 = (is_cell ? (c0f + b * 256) : (A1 + b * 512)) + h;
        const float* l1 = (is_cell ? c1f : h1f) + b * 256 + h;
        val.x = l0[0]; val.y = l1[0];   // h=2q,   l=0 / l=1
        val.z = l0[1]; val.w = l1[1];   // h=2q+1, l=0 / l=1
    } else {
        const float4* src = (const float4*)(is_cell ? cel : hid);
        val = src[vv];
    }
    float4* dst = (float4*)(out + 1024 + (is_cell ? STACK_ELEMS : 0));
    dst[vv] = val;
}

// ---------------------------------------------------------------------------
extern "C" void kernel_launch(void* const* d_in, const int* in_sizes, int n_in,
                              void* d_out, int out_size, void* d_ws, size_t ws_size,
                              hipStream_t stream) {
    const float* x    = (const float*)d_in[0];
    const float* hid  = (const float*)d_in[1];
    const float* cel  = (const float*)d_in[2];
    const float* wih0 = (const float*)d_in[3];
    const float* whh0 = (const float*)d_in[4];
    const float* bih0 = (const float*)d_in[5];
    const float* bhh0 = (const float*)d_in[6];
    const float* wih1 = (const float*)d_in[7];
    const float* whh1 = (const float*)d_in[8];
    const float* bih1 = (const float*)d_in[9];
    const float* bhh1 = (const float*)d_in[10];
    const int* op  = (const int*)d_in[11];
    const int* pos = (const int*)d_in[12];
    float* out = (float*)d_out;

    // workspace layout (floats): ~3.25 MiB
    float* W    = (float*)d_ws;
    float* A0   = W;                // 256x512: [x | h0_in]
    float* A1   = W + 131072;       // 256x512: [h0 | h1_in]
    float* c0in = W + 262144;       // 256x256
    float* c1in = W + 327680;
    float* gates= W + 393216;       // 256x1024 (reused by both layers)
    float* c0f  = W + 655360;       // layer-0 c out
    float* h1f  = W + 720896;       // layer-1 h out
    float* c1f  = W + 786432;       // layer-1 c out

    gather_k<<<256, 256, 0, stream>>>(x, hid, cel, pos, A0, A1, c0in, c1in);
    gemm_k<<<128, 256, 0, stream>>>(A0, wih0, whh0, bih0, bhh0, gates);
    act_k<<<256, 256, 0, stream>>>(gates, c0in, A1, 512, c0f);   // h0 -> A1[:,0:256]
    gemm_k<<<128, 256, 0, stream>>>(A1, wih1, whh1, bih1, bhh1, gates);
    act_k<<<256, 256, 0, stream>>>(gates, c1in, h1f, 256, c1f);
    copy_k<<<NCOPY_BLOCKS + 1, 256, 0, stream>>>(
        hid, cel, pos, op, A1, h1f, c0f, c1f, out);
}

// Round 4
// 284.820 us; speedup vs baseline: 1.0961x; 1.0961x over previous
//
#include <hip/hip_runtime.h>

// StackLSTMCell: B=256, IN=256, H=256, L=2, S=128 (SLOTS=129). All f32.
// 4 kernels: gemm0 (A gathered from x|hid-l0) -> act0 -> gemm1 (A from
// h0f|hid-l1) -> copy (stack passthrough + inline layer-1 act on the pos+1
// slot + finalize).

static __device__ __forceinline__ float sigf(float x) {
    return 1.0f / (1.0f + __expf(-x));
}
static __device__ __forceinline__ float tanh_fast(float x) {
    return 2.0f / (1.0f + __expf(-2.0f * x)) - 1.0f;
}

// ---------------------------------------------------------------------------
// GEMM: gates(256x1024) = A(256x512) @ [w_ih | w_hh]^T + b_ih + b_hh
// A row b: k<256 -> a_lo[b*256+k] (x or h0f); k>=256 -> a_hi[(gather)*2]
// (hid + l, stride 2 over the (h,l)-interleaved stack at slot pos[b]).
// Tiling: BM=16 x BN=64 x BK=32, grid = 16*16 = 256 blocks, 256 threads.
#define GBM 16
#define GBN 64
#define GBK 32

__global__ __launch_bounds__(256) void gemm_k(
    const float* __restrict__ a_lo,    // 256 x 256, stride 1
    const float* __restrict__ a_hi,    // hid + l    (stride 2 gather at pos)
    const int*   __restrict__ pos,
    const float* __restrict__ wih,     // 1024 x 256
    const float* __restrict__ whh,     // 1024 x 256
    const float* __restrict__ bih,
    const float* __restrict__ bhh,
    float* __restrict__ gates)
{
    __shared__ float As[GBK][GBM + 1];   // row stride 17 floats
    __shared__ float Ws[GBK][GBN + 4];   // row stride 68 floats (16B aligned)
    int t   = threadIdx.x;
    int bm0 = (blockIdx.x >> 4) * GBM;
    int jt0 = (blockIdx.x & 15) * GBN;
    // staging assignments
    int arow = t >> 4;            // 0..15
    int akk  = (t & 15) * 2;      // 0..30 (float2 of k)
    int wrow = t >> 2;            // 0..63
    int wkb  = (t & 3) * 8;       // 0,8,16,24
    // compute assignments
    int tx = t & 15, ty = t >> 4;
    int ab = bm0 + arow;
    int ap = pos[ab];
    int wj = jt0 + wrow;

    float2 apre;
    float4 wpre0, wpre1;
    {   // prefetch tile kt=0
        int k = akk;              // < 256 always at kt=0
        apre = *(const float2*)&a_lo[ab * 256 + k];
        const float* ws = &wih[wj * 256 + wkb];
        wpre0 = *(const float4*)ws;
        wpre1 = *(const float4*)(ws + 4);
    }
    float acc[4] = {0.f, 0.f, 0.f, 0.f};
    for (int kt = 0; kt < 512; kt += GBK) {
        __syncthreads();
        As[akk][arow]     = apre.x;
        As[akk + 1][arow] = apre.y;
        Ws[wkb][wrow]     = wpre0.x;
        Ws[wkb + 1][wrow] = wpre0.y;
        Ws[wkb + 2][wrow] = wpre0.z;
        Ws[wkb + 3][wrow] = wpre0.w;
        Ws[wkb + 4][wrow] = wpre1.x;
        Ws[wkb + 5][wrow] = wpre1.y;
        Ws[wkb + 6][wrow] = wpre1.z;
        Ws[wkb + 7][wrow] = wpre1.w;
        int kt2 = kt + GBK;
        if (kt2 < 512) {          // prefetch next tile; latency hides under FMA
            int k = kt2 + akk;
            if (k < 256) {
                apre = *(const float2*)&a_lo[ab * 256 + k];
            } else {
                const float* ah = a_hi + ((ap * 256 + ab) * 256 + (k - 256)) * 2;
                apre.x = ah[0];
                apre.y = ah[2];
            }
            int kk = kt2 + wkb;
            const float* ws = (kk < 256) ? &wih[wj * 256 + kk]
                                         : &whh[wj * 256 + kk - 256];
            wpre0 = *(const float4*)ws;
            wpre1 = *(const float4*)(ws + 4);
        }
        __syncthreads();
        #pragma unroll
        for (int k = 0; k < GBK; ++k) {
            float a   = As[k][ty];
            float4 bv = *(const float4*)&Ws[k][tx * 4];
            acc[0] = fmaf(a, bv.x, acc[0]);
            acc[1] = fmaf(a, bv.y, acc[1]);
            acc[2] = fmaf(a, bv.z, acc[2]);
            acc[3] = fmaf(a, bv.w, acc[3]);
        }
    }
    int j = jt0 + tx * 4;
    float4 b0 = *(const float4*)&bih[j];
    float4 b1 = *(const float4*)&bhh[j];
    float4 r;
    r.x = acc[0] + b0.x + b1.x;
    r.y = acc[1] + b0.y + b1.y;
    r.z = acc[2] + b0.z + b1.z;
    r.w = acc[3] + b0.w + b1.w;
    *(float4*)&gates[(bm0 + ty) * 1024 + j] = r;
}

// ---------------------------------------------------------------------------
// Layer-0 activation: gate order i,f,g,o; c_in gathered from cel l=0 at pos.
__global__ __launch_bounds__(256) void act0_k(
    const float* __restrict__ gates,
    const float* __restrict__ cel,
    const int*   __restrict__ pos,
    float* __restrict__ h0f, float* __restrict__ c0f)
{
    int e = blockIdx.x * 256 + threadIdx.x;   // 65536 = B*H
    int b = e >> 8, h = e & 255;
    float cin = cel[((pos[b] * 256 + b) * 256 + h) * 2];   // l=0
    const float* g = gates + b * 1024 + h;
    float gi = g[0], gf = g[256], gg = g[512], go = g[768];
    float c  = sigf(gf) * cin + sigf(gi) * tanh_fast(gg);
    h0f[e] = sigf(go) * tanh_fast(c);
    c0f[e] = c;
}

// ---------------------------------------------------------------------------
// Copy both stacks to d_out with the pos+1 slot replaced (layer-1 activation
// computed inline from gates); one extra block writes h_out/c_out.
#define NV4_PER_STACK 4227072     // 129*256*256*2/4
#define NCOPY_BLOCKS  33024       // 2*NV4_PER_STACK/256 (exact)
#define STACK_ELEMS   16908288    // 129*256*256*2

static __device__ __forceinline__ void lstm1(
    const float* __restrict__ gates, const float* __restrict__ cel,
    int p, int b, int h, float& hv, float& cv)
{
    float cin = cel[((p * 256 + b) * 256 + h) * 2 + 1];    // l=1
    const float* g = gates + b * 1024 + h;
    float gi = g[0], gf = g[256], gg = g[512], go = g[768];
    cv = sigf(gf) * cin + sigf(gi) * tanh_fast(gg);
    hv = sigf(go) * tanh_fast(cv);
}

__global__ __launch_bounds__(256) void copy_k(
    const float* __restrict__ hid, const float* __restrict__ cel,
    const int* __restrict__ pos, const int* __restrict__ op,
    const float* __restrict__ h0f, const float* __restrict__ c0f,
    const float* __restrict__ gates,
    float* __restrict__ out)
{
    if (blockIdx.x == NCOPY_BLOCKS) {
        // finalize: h_out (1,B,L) at out[0..511], c_out at out[512..1023]
        int b = threadIdx.x;
        int o = op[b];
        int p = pos[b];
        float h0v, h1v, c0v, c1v;
        if (o == 1) {            // new_pos == pos+1: freshly computed slot
            h0v = h0f[b * 256 + 255];
            c0v = c0f[b * 256 + 255];
            lstm1(gates, cel, p, b, 255, h1v, c1v);
        } else {                 // untouched slot: passthrough from input
            int base2 = (((p + o) * 256 + b) * 256 + 255) * 2;
            h0v = hid[base2]; h1v = hid[base2 + 1];
            c0v = cel[base2]; c1v = cel[base2 + 1];
        }
        out[b * 2]           = h0v;
        out[b * 2 + 1]       = h1v;
        out[512 + b * 2]     = c0v;
        out[512 + b * 2 + 1] = c1v;
        return;
    }
    int v = blockIdx.x * 256 + threadIdx.x;
    bool is_cell = v >= NV4_PER_STACK;
    int vv = is_cell ? v - NV4_PER_STACK : v;
    int s   = vv >> 15;        // float4s per slot = 256*128 = 32768
    int rem = vv & 32767;
    int b   = rem >> 7;        // float4s per (b) plane = 128
    int q   = rem & 127;       // elems 4q..4q+3 = (h=2q..2q+1, l=0..1)
    int p   = pos[b];
    float4 val;
    if (s == p + 1) {
        int h = q * 2;
        float h1a, c1a, h1b, c1b;
        lstm1(gates, cel, p, b, h,     h1a, c1a);
        lstm1(gates, cel, p, b, h + 1, h1b, c1b);
        if (is_cell) {
            val.x = c0f[b * 256 + h];     val.y = c1a;
            val.z = c0f[b * 256 + h + 1]; val.w = c1b;
        } else {
            val.x = h0f[b * 256 + h];     val.y = h1a;
            val.z = h0f[b * 256 + h + 1]; val.w = h1b;
        }
    } else {
        const float4* src = (const float4*)(is_cell ? cel : hid);
        val = src[vv];
    }
    float4* dst = (float4*)(out + 1024 + (is_cell ? STACK_ELEMS : 0));
    dst[vv] = val;
}

// ---------------------------------------------------------------------------
extern "C" void kernel_launch(void* const* d_in, const int* in_sizes, int n_in,
                              void* d_out, int out_size, void* d_ws, size_t ws_size,
                              hipStream_t stream) {
    const float* x    = (const float*)d_in[0];
    const float* hid  = (const float*)d_in[1];
    const float* cel  = (const float*)d_in[2];
    const float* wih0 = (const float*)d_in[3];
    const float* whh0 = (const float*)d_in[4];
    const float* bih0 = (const float*)d_in[5];
    const float* bhh0 = (const float*)d_in[6];
    const float* wih1 = (const float*)d_in[7];
    const float* whh1 = (const float*)d_in[8];
    const float* bih1 = (const float*)d_in[9];
    const float* bhh1 = (const float*)d_in[10];
    const int* op  = (const int*)d_in[11];
    const int* pos = (const int*)d_in[12];
    float* out = (float*)d_out;

    // workspace: gates 256x1024, h0f 256x256, c0f 256x256 (f32)
    float* W    = (float*)d_ws;
    float* gates= W;
    float* h0f  = W + 262144;
    float* c0f  = W + 327680;

    gemm_k<<<256, 256, 0, stream>>>(x,   hid,     pos, wih0, whh0, bih0, bhh0, gates);
    act0_k<<<256, 256, 0, stream>>>(gates, cel, pos, h0f, c0f);
    gemm_k<<<256, 256, 0, stream>>>(h0f, hid + 1, pos, wih1, whh1, bih1, bhh1, gates);
    copy_k<<<NCOPY_BLOCKS + 1, 256, 0, stream>>>(
        hid, cel, pos, op, h0f, c0f, gates, out);
}